// Round 2
// baseline (176.101 us; speedup 1.0000x reference)
//
#include <hip/hip_runtime.h>
#include <math.h>

#define TT 2048
#define HH 128
#define ROWS 8
#define SP 132  // LDS row stride in floats
#define NBLK (TT / ROWS)

__device__ __forceinline__ float dot4(float4 a, float4 b) {
    return a.x * b.x + a.y * b.y + a.z * b.z + a.w * b.w;
}

// ---------------- prep: transpose/pack weights for coalesced column-major streaming ----
__global__ __launch_bounds__(256) void prep_kernel(
        const float* __restrict__ w_in, const float* __restrict__ w_out,
        const float* __restrict__ w_v, const float* __restrict__ w_q,
        const float* __restrict__ w_k, const float* __restrict__ w_o,
        const float* __restrict__ w_ff,
        float4* __restrict__ win_p, float4* __restrict__ wout_p,
        float4* __restrict__ wcat, float4* __restrict__ wff_p) {
    int i = blockIdx.x * 256 + threadIdx.x;
    if (i < 4096) {
        int cg = i >> 7, col = i & 127;
        win_p[i] = ((const float4*)w_in)[col * 32 + cg];
    } else if (i < 8192) {
        int j = i - 4096, cg = j >> 7, col = j & 127;
        wout_p[j] = ((const float4*)w_out)[col * 32 + cg];
    } else if (i < 40960) {
        int j = i - 8192;
        int l = j >> 14, r = j & 16383, cg = r >> 9, col = r & 511;
        int sel = col >> 7, cm = col & 127;
        const float* s = (sel == 0 ? w_v : sel == 1 ? w_q : sel == 2 ? w_k : w_o) + l * HH * HH;
        wcat[j] = ((const float4*)s)[cm * 32 + cg];
    } else {
        int j = i - 40960;
        int l = j >> 13, r = j & 8191, cg = r >> 7, col = r & 127;
        const float* s = w_ff + l * HH * 256;
        wff_p[j] = ((const float4*)s)[col * 64 + cg];
    }
}

// ---- device-wide barrier: all NBLK blocks co-resident (256 blocks <= 256 CUs). ----
__device__ __forceinline__ void grid_barrier(unsigned* __restrict__ ctr) {
    __syncthreads();  // all block writes drained (vmcnt0) before arrive
    if (threadIdx.x == 0) {
        __threadfence();          // agent-scope release: flush XCD L2
        atomicAdd(ctr, 1u);
        while (__hip_atomic_load(ctr, __ATOMIC_RELAXED, __HIP_MEMORY_SCOPE_AGENT)
               < (unsigned)NBLK) {
            __builtin_amdgcn_s_sleep(8);
        }
        __threadfence();          // agent-scope acquire: invalidate stale lines
    }
    __syncthreads();
}

// ---- attention: wave wv owns row t0+wv; q,o from LDS; k,v,g,i from global. ----
__device__ __forceinline__ void attn_row(int t0,
        const float* __restrict__ kb, const float* __restrict__ vb,
        const float* __restrict__ qs, const float* __restrict__ os,
        const float* __restrict__ g, const float* __restrict__ iexp,
        float* __restrict__ hs) {
    int tid = threadIdx.x;
    int wv = tid >> 6, lane = tid & 63;
    int t = t0 + wv;
    float2 q2 = *(const float2*)(qs + wv * SP + 2 * lane);
    float2 o2 = *(const float2*)(os + wv * SP + 2 * lane);
    int tp = t;
    float2 k2 = *(const float2*)(kb + tp * HH + 2 * lane);
    float2 v2 = *(const float2*)(vb + tp * HH + 2 * lane);
    float ie = iexp[tp], gv = g[tp];
    float nx = 0.f, ny = 0.f, dsum = 0.f, decay = 1.f;
    while (true) {
        bool cont = (tp > 0) && (gv != 0.f);
        float2 k2n = {0.f, 0.f}, v2n = {0.f, 0.f};
        float ien = 0.f, gvn = 0.f;
        if (cont) {  // prefetch next step; overlaps the reduce below
            k2n = *(const float2*)(kb + (tp - 1) * HH + 2 * lane);
            v2n = *(const float2*)(vb + (tp - 1) * HH + 2 * lane);
            ien = iexp[tp - 1]; gvn = g[tp - 1];
        }
        float p = k2.x * q2.x + k2.y * q2.y;
#pragma unroll
        for (int off = 1; off <= 32; off <<= 1) p += __shfl_xor(p, off, 64);
        float coeff = decay * ie * p;
        nx += coeff * v2.x; ny += coeff * v2.y; dsum += coeff;
        if (!cont) break;
        decay *= gv;
        tp--; k2 = k2n; v2 = v2n; ie = ien; gv = gvn;
    }
    float inv = 1.f / fmaxf(fabsf(dsum), 1.f);
    *(float2*)(hs + wv * SP + 2 * lane) = make_float2(o2.x * nx * inv, o2.y * ny * inv);
}

// ---- f/i scalar gates: wave wv handles row wv. ----
__device__ __forceinline__ void proj_fi(int t0, const float* __restrict__ xls,
        const float* __restrict__ w_f, const float* __restrict__ b_f,
        const float* __restrict__ w_i, const float* __restrict__ b_i,
        const int* __restrict__ start, float* __restrict__ g, float* __restrict__ iexp) {
    int tid = threadIdx.x;
    int wv = tid >> 6, lane = tid & 63;
    const float* x = xls + wv * SP + 2 * lane;
    float pf = x[0] * w_f[2 * lane] + x[1] * w_f[2 * lane + 1];
    float pi = x[0] * w_i[2 * lane] + x[1] * w_i[2 * lane + 1];
#pragma unroll
    for (int off = 1; off <= 32; off <<= 1) {
        pf += __shfl_xor(pf, off, 64);
        pi += __shfl_xor(pi, off, 64);
    }
    if (lane == 0) {
        int t = t0 + wv;
        g[t] = start[t] ? 0.f : 1.f / (1.f + expf(-(pf + b_f[0])));
        iexp[t] = expf(pi + b_i[0]);
    }
}

// ---- 4 projections, column-major (thread = col). k,v -> global; q,o -> LDS. ----
__device__ __forceinline__ void proj_block(int t0, const float* __restrict__ xls,
        const float4* __restrict__ wcat,
        const float* __restrict__ b_v, const float* __restrict__ b_q,
        const float* __restrict__ b_k, const float* __restrict__ b_o,
        float* __restrict__ kb, float* __restrict__ vb,
        float* __restrict__ qs, float* __restrict__ os) {
    int tid = threadIdx.x;
    int col = tid, mat = tid >> 7, cm = tid & 127;  // mat is wave-uniform
    float acc[8] = {0.f, 0.f, 0.f, 0.f, 0.f, 0.f, 0.f, 0.f};
#pragma unroll 8
    for (int cg = 0; cg < 32; ++cg) {
        float4 w4 = wcat[cg * 512 + col];
#pragma unroll
        for (int r = 0; r < 8; ++r) {
            float4 x4 = *(const float4*)(xls + r * SP + 4 * cg);
            acc[r] += dot4(x4, w4);
        }
    }
    const float ks = 0.088388347648318447f;  // 1/sqrt(128)
    if (mat == 0) {
        float bb = b_v[cm];
#pragma unroll
        for (int r = 0; r < 8; ++r) vb[(t0 + r) * HH + cm] = acc[r] + bb;
    } else if (mat == 1) {
        float bb = b_q[cm];
#pragma unroll
        for (int r = 0; r < 8; ++r) qs[r * SP + cm] = acc[r] + bb;
    } else if (mat == 2) {
        float bb = b_k[cm];
#pragma unroll
        for (int r = 0; r < 8; ++r) kb[(t0 + r) * HH + cm] = acc[r] * ks + bb;
    } else {
        float bb = b_o[cm];
#pragma unroll
        for (int r = 0; r < 8; ++r) os[r * SP + cm] = 1.f / (1.f + expf(-(acc[r] + bb)));
    }
}

// ---- ff: z = lrelu([h, e] @ w_ff.T + b_ff); thread = (col, row-pair). ----
__device__ __forceinline__ void ff_block(const float* __restrict__ hsb,
        const float* __restrict__ esb, const float4* __restrict__ wff,
        const float* __restrict__ b_ff, float* __restrict__ zs) {
    int tid = threadIdx.x;
    int col = tid & 127, rg = tid >> 7;
    int r0 = 2 * rg, r1 = r0 + 1;
    float a0 = 0.f, a1 = 0.f;
#pragma unroll 8
    for (int cg = 0; cg < 32; ++cg) {
        float4 w4 = wff[cg * 128 + col];
        a0 += dot4(*(const float4*)(hsb + r0 * SP + 4 * cg), w4);
        a1 += dot4(*(const float4*)(hsb + r1 * SP + 4 * cg), w4);
    }
#pragma unroll 8
    for (int cg = 32; cg < 64; ++cg) {
        float4 w4 = wff[cg * 128 + col];
        int c = 4 * (cg - 32);
        a0 += dot4(*(const float4*)(esb + r0 * SP + c), w4);
        a1 += dot4(*(const float4*)(esb + r1 * SP + c), w4);
    }
    float bb = b_ff[col];
    a0 += bb; a1 += bb;
    a0 = a0 > 0.f ? a0 : 0.01f * a0;
    a1 = a1 > 0.f ? a1 : 0.01f * a1;
    zs[r0 * SP + col] = a0;
    zs[r1 * SP + col] = a1;
}

// ---- generic 128->128 dense; yg (global) and/or ys (LDS) may be null. ----
__device__ __forceinline__ void dense128(int t0, const float* __restrict__ xls,
        const float4* __restrict__ Wp, const float* __restrict__ b,
        float* __restrict__ yg, float* __restrict__ ys) {
    int tid = threadIdx.x;
    int col = tid & 127, rg = tid >> 7;
    int r0 = 2 * rg, r1 = r0 + 1;
    float a0 = 0.f, a1 = 0.f;
#pragma unroll 8
    for (int cg = 0; cg < 32; ++cg) {
        float4 w4 = Wp[cg * 128 + col];
        a0 += dot4(*(const float4*)(xls + r0 * SP + 4 * cg), w4);
        a1 += dot4(*(const float4*)(xls + r1 * SP + 4 * cg), w4);
    }
    float bb = b[col];
    a0 += bb; a1 += bb;
    if (yg) {
        yg[(t0 + r0) * HH + col] = a0;
        yg[(t0 + r1) * HH + col] = a1;
    }
    if (ys) {
        ys[r0 * SP + col] = a0;
        ys[r1 * SP + col] = a1;
    }
}

// ---------------- fused: e + proj0 | barrier | attn0+ff0+proj1 | barrier | attn1+ff1+out
__global__ __launch_bounds__(512, 2) void mega_kernel(
        const float* __restrict__ emb, const int* __restrict__ start,
        const float4* __restrict__ win_p, const float* __restrict__ b_in,
        const float4* __restrict__ wcat,
        const float* __restrict__ b_v, const float* __restrict__ b_q,
        const float* __restrict__ b_k, const float* __restrict__ b_o,
        const float* __restrict__ w_f, const float* __restrict__ b_f,
        const float* __restrict__ w_i, const float* __restrict__ b_i,
        const float4* __restrict__ wff_p, const float* __restrict__ b_ff,
        const float4* __restrict__ wout_p, const float* __restrict__ b_out,
        float* __restrict__ k0b, float* __restrict__ v0b,
        float* __restrict__ k1b, float* __restrict__ v1b,
        float* __restrict__ g0, float* __restrict__ i0,
        float* __restrict__ g1, float* __restrict__ i1,
        unsigned* __restrict__ bar,
        float* __restrict__ out) {
    __shared__ float xs[ROWS * SP];
    __shared__ float es[ROWS * SP];
    __shared__ float hs[ROWS * SP];
    __shared__ float zs[ROWS * SP];
    __shared__ float qs[ROWS * SP];
    __shared__ float os[ROWS * SP];
    int tid = threadIdx.x;
    int t0 = blockIdx.x * ROWS;
    int wv = tid >> 6, lane = tid & 63;

    // ---- P0: e = emb @ w_in.T + b_in (LDS only); layer-0 projections ----
    *(float2*)(xs + wv * SP + 2 * lane) = *(const float2*)(emb + (t0 + wv) * HH + 2 * lane);
    __syncthreads();
    dense128(t0, xs, win_p, b_in, (float*)0, es);
    __syncthreads();
    proj_block(t0, es, wcat, b_v, b_q, b_k, b_o, k0b, v0b, qs, os);
    proj_fi(t0, es, w_f, b_f, w_i, b_i, start, g0, i0);
    grid_barrier(bar + 0);

    // ---- P1: attn0 + ff0 + layer-1 projections ----
    attn_row(t0, k0b, v0b, qs, os, g0, i0, hs);
    __syncthreads();
    ff_block(hs, es, wff_p, b_ff, zs);
    __syncthreads();
    proj_block(t0, zs, wcat + 16384, b_v + HH, b_q + HH, b_k + HH, b_o + HH,
               k1b, v1b, qs, os);
    proj_fi(t0, zs, w_f + HH, b_f + 1, w_i + HH, b_i + 1, start, g1, i1);
    grid_barrier(bar + 1);

    // ---- P2: attn1 + ff1 + final dense ----
    attn_row(t0, k1b, v1b, qs, os, g1, i1, hs);
    __syncthreads();
    ff_block(hs, es, wff_p + 8192, b_ff + HH, zs);
    __syncthreads();
    dense128(t0, zs, wout_p, b_out, out, (float*)0);
}

extern "C" void kernel_launch(void* const* d_in, const int* in_sizes, int n_in,
                              void* d_out, int out_size, void* d_ws, size_t ws_size,
                              hipStream_t stream) {
    const float* emb   = (const float*)d_in[0];
    const int*   start = (const int*)  d_in[1];
    const float* w_in  = (const float*)d_in[2];
    const float* b_in  = (const float*)d_in[3];
    const float* w_out = (const float*)d_in[4];
    const float* b_out = (const float*)d_in[5];
    const float* w_f   = (const float*)d_in[6];
    const float* b_f   = (const float*)d_in[7];
    const float* w_i   = (const float*)d_in[8];
    const float* b_i   = (const float*)d_in[9];
    const float* w_v   = (const float*)d_in[10];
    const float* b_v   = (const float*)d_in[11];
    const float* w_q   = (const float*)d_in[12];
    const float* b_q   = (const float*)d_in[13];
    const float* w_k   = (const float*)d_in[14];
    const float* b_k   = (const float*)d_in[15];
    const float* w_o   = (const float*)d_in[16];
    const float* b_o   = (const float*)d_in[17];
    const float* w_ff  = (const float*)d_in[18];
    const float* b_ff  = (const float*)d_in[19];
    float* out = (float*)d_out;

    unsigned* bar = (unsigned*)d_ws;            // 2 counters, poison-cleared below
    float* ws = (float*)d_ws + 64;
    float* k0b = ws; ws += TT * HH;
    float* v0b = ws; ws += TT * HH;
    float* k1b = ws; ws += TT * HH;
    float* v1b = ws; ws += TT * HH;
    float* g0  = ws; ws += TT;
    float* i0  = ws; ws += TT;
    float* g1  = ws; ws += TT;
    float* i1  = ws; ws += TT;
    float4* win_p  = (float4*)ws; ws += 16384;   // 4096 float4
    float4* wout_p = (float4*)ws; ws += 16384;   // 4096 float4
    float4* wcat   = (float4*)ws; ws += 131072;  // 32768 float4 (2 layers)
    float4* wff_p  = (float4*)ws; ws += 65536;   // 16384 float4 (2 layers)

    hipMemsetAsync(bar, 0, 64, stream);  // barrier counters must start at 0 each replay
    prep_kernel<<<dim3(224), dim3(256), 0, stream>>>(
        w_in, w_out, w_v, w_q, w_k, w_o, w_ff, win_p, wout_p, wcat, wff_p);
    mega_kernel<<<dim3(NBLK), dim3(512), 0, stream>>>(
        emb, start, win_p, b_in, wcat,
        b_v, b_q, b_k, b_o, w_f, b_f, w_i, b_i,
        wff_p, b_ff, wout_p, b_out,
        k0b, v0b, k1b, v1b, g0, i0, g1, i1,
        bar, out);
}

// Round 3
// 163.814 us; speedup vs baseline: 1.0750x; 1.0750x over previous
//
#include <hip/hip_runtime.h>
#include <math.h>

#define TT 2048
#define HH 128
#define ROWS 8
#define SP 132   // row-major LDS stride (qs, os)
#define XR 144   // chunk-padded LDS row stride: 4 chunks x 36
#define NBLK (TT / ROWS)

__device__ __forceinline__ float dot4(float4 a, float4 b) {
    return a.x * b.x + a.y * b.y + a.z * b.z + a.w * b.w;
}

// chunk-padded x index: element k of row r lives at r*XR + (k>>5)*36 + (k&31)
__device__ __forceinline__ int xidx(int r, int k) {
    return r * XR + ((k >> 5) * 36) + (k & 31);
}

// ---------------- prep: pack weights [k4][col] column-major + zero barrier ctrs ----
__global__ __launch_bounds__(256) void prep_kernel(
        const float* __restrict__ w_in, const float* __restrict__ w_out,
        const float* __restrict__ w_v, const float* __restrict__ w_q,
        const float* __restrict__ w_k, const float* __restrict__ w_o,
        const float* __restrict__ w_ff,
        float4* __restrict__ win_p, float4* __restrict__ wout_p,
        float4* __restrict__ wcat, float4* __restrict__ wff_p,
        unsigned* __restrict__ bar) {
    int i = blockIdx.x * 256 + threadIdx.x;
    if (blockIdx.x == 0 && threadIdx.x < 16) bar[threadIdx.x] = 0u;
    if (i < 4096) {
        int cg = i >> 7, col = i & 127;
        win_p[i] = ((const float4*)w_in)[col * 32 + cg];
    } else if (i < 8192) {
        int j = i - 4096, cg = j >> 7, col = j & 127;
        wout_p[j] = ((const float4*)w_out)[col * 32 + cg];
    } else if (i < 40960) {
        int j = i - 8192;
        int l = j >> 14, r = j & 16383, cg = r >> 9, col = r & 511;
        int sel = col >> 7, cm = col & 127;
        const float* s = (sel == 0 ? w_v : sel == 1 ? w_q : sel == 2 ? w_k : w_o) + l * HH * HH;
        wcat[j] = ((const float4*)s)[cm * 32 + cg];
    } else {
        int j = i - 40960;
        int l = j >> 13, r = j & 8191, cg = r >> 7, col = r & 127;
        const float* s = w_ff + l * HH * 256;
        wff_p[j] = ((const float4*)s)[col * 64 + cg];
    }
}

// ---- device-wide barrier: 256 blocks on 256 CUs, all co-resident. ----
__device__ __forceinline__ void grid_barrier(unsigned* __restrict__ ctr) {
    __syncthreads();
    if (threadIdx.x == 0) {
        __threadfence();
        atomicAdd(ctr, 1u);
        while (__hip_atomic_load(ctr, __ATOMIC_RELAXED, __HIP_MEMORY_SCOPE_AGENT)
               < (unsigned)NBLK) {
            __builtin_amdgcn_s_sleep(8);
        }
        __threadfence();
    }
    __syncthreads();
}

// ---- K-split GEMV core (N=128): acc[h][rr] over rows rg*4+rr, cols cslot+64h,
//      K-chunk kc (32 of 128). x read as 4-way bank-disjoint multicast b128. ----
__device__ __forceinline__ void gemv128(int rg, int kc, int cslot,
        const float* __restrict__ xs, const float4* __restrict__ Wp, int k4base,
        float acc[2][4]) {
#pragma unroll
    for (int j = 0; j < 8; ++j) {
        int k4 = k4base + kc * 8 + j;
        float4 w0 = Wp[k4 * 128 + cslot];
        float4 w1 = Wp[k4 * 128 + 64 + cslot];
#pragma unroll
        for (int rr = 0; rr < 4; ++rr) {
            float4 x4 = *(const float4*)(xs + (rg * 4 + rr) * XR + kc * 36 + 4 * j);
            acc[0][rr] += dot4(x4, w0);
            acc[1][rr] += dot4(x4, w1);
        }
    }
}

__device__ __forceinline__ void reduce_kc(float* v) {
    *v += __shfl_xor(*v, 16, 64);
    *v += __shfl_xor(*v, 32, 64);
}

// ---- attention: wave wv owns row t0+wv; q,o from LDS row-major; k,v,g,i global. ----
__device__ __forceinline__ void attn_row(int t0,
        const float* __restrict__ kb, const float* __restrict__ vb,
        const float* __restrict__ qs, const float* __restrict__ os,
        const float* __restrict__ g, const float* __restrict__ iexp,
        float* __restrict__ hs) {
    int tid = threadIdx.x;
    int wv = tid >> 6, lane = tid & 63;
    int t = t0 + wv;
    float2 q2 = *(const float2*)(qs + wv * SP + 2 * lane);
    float2 o2 = *(const float2*)(os + wv * SP + 2 * lane);
    int tp = t;
    float2 k2 = *(const float2*)(kb + tp * HH + 2 * lane);
    float2 v2 = *(const float2*)(vb + tp * HH + 2 * lane);
    float ie = iexp[tp], gv = g[tp];
    float nx = 0.f, ny = 0.f, dsum = 0.f, decay = 1.f;
    while (true) {
        bool cont = (tp > 0) && (gv != 0.f);
        float2 k2n = {0.f, 0.f}, v2n = {0.f, 0.f};
        float ien = 0.f, gvn = 0.f;
        if (cont) {  // prefetch next step; overlaps the reduce below
            k2n = *(const float2*)(kb + (tp - 1) * HH + 2 * lane);
            v2n = *(const float2*)(vb + (tp - 1) * HH + 2 * lane);
            ien = iexp[tp - 1]; gvn = g[tp - 1];
        }
        float p = k2.x * q2.x + k2.y * q2.y;
#pragma unroll
        for (int off = 1; off <= 32; off <<= 1) p += __shfl_xor(p, off, 64);
        float coeff = decay * ie * p;
        nx += coeff * v2.x; ny += coeff * v2.y; dsum += coeff;
        if (!cont) break;
        decay *= gv;
        tp--; k2 = k2n; v2 = v2n; ie = ien; gv = gvn;
    }
    float inv = 1.f / fmaxf(fabsf(dsum), 1.f);
    int d = 2 * lane;
    *(float2*)(hs + wv * XR + (d >> 5) * 36 + (d & 31)) =
        make_float2(o2.x * nx * inv, o2.y * ny * inv);
}

// ---- f/i scalar gates: wave wv handles row wv; x in chunk-padded layout. ----
__device__ __forceinline__ void proj_fi(int t0, const float* __restrict__ xls,
        const float* __restrict__ w_f, const float* __restrict__ b_f,
        const float* __restrict__ w_i, const float* __restrict__ b_i,
        const int* __restrict__ start, float* __restrict__ g, float* __restrict__ iexp) {
    int tid = threadIdx.x;
    int wv = tid >> 6, lane = tid & 63;
    int d = 2 * lane;
    float2 xv = *(const float2*)(xls + wv * XR + (d >> 5) * 36 + (d & 31));
    float pf = xv.x * w_f[d] + xv.y * w_f[d + 1];
    float pi = xv.x * w_i[d] + xv.y * w_i[d + 1];
#pragma unroll
    for (int off = 1; off <= 32; off <<= 1) {
        pf += __shfl_xor(pf, off, 64);
        pi += __shfl_xor(pi, off, 64);
    }
    if (lane == 0) {
        int t = t0 + wv;
        g[t] = start[t] ? 0.f : 1.f / (1.f + expf(-(pf + b_f[0])));
        iexp[t] = expf(pi + b_i[0]);
    }
}

// ---- 4 projections fused, K-split: k,v -> global; q,o -> LDS row-major. ----
__device__ __forceinline__ void proj_block(int t0, const float* __restrict__ xls,
        const float4* __restrict__ wc,
        const float* __restrict__ b_v, const float* __restrict__ b_q,
        const float* __restrict__ b_k, const float* __restrict__ b_o,
        float* __restrict__ kb, float* __restrict__ vb,
        float* __restrict__ qs, float* __restrict__ os) {
    int tid = threadIdx.x;
    int lane = tid & 63, wv = tid >> 6;
    int kc = lane >> 4, c = lane & 15;
    int rg = wv >> 2, cslot = (wv & 3) * 16 + c;
    float acc[4][2][4] = {};
#pragma unroll
    for (int j = 0; j < 8; ++j) {
        int k4 = kc * 8 + j;
        const float4* wb = wc + k4 * 512;
        float4 w[4][2];
#pragma unroll
        for (int m = 0; m < 4; ++m) {
            w[m][0] = wb[m * 128 + cslot];
            w[m][1] = wb[m * 128 + 64 + cslot];
        }
#pragma unroll
        for (int rr = 0; rr < 4; ++rr) {
            float4 x4 = *(const float4*)(xls + (rg * 4 + rr) * XR + kc * 36 + 4 * j);
#pragma unroll
            for (int m = 0; m < 4; ++m) {
                acc[m][0][rr] += dot4(x4, w[m][0]);
                acc[m][1][rr] += dot4(x4, w[m][1]);
            }
        }
    }
#pragma unroll
    for (int m = 0; m < 4; ++m)
#pragma unroll
        for (int h = 0; h < 2; ++h)
#pragma unroll
            for (int rr = 0; rr < 4; ++rr) reduce_kc(&acc[m][h][rr]);
    const float ks = 0.088388347648318447f;  // 1/sqrt(128)
    if (kc == 0) {
#pragma unroll
        for (int h = 0; h < 2; ++h) {
            int col = cslot + 64 * h;
            float bv = b_v[col], bq = b_q[col], bk = b_k[col], bo = b_o[col];
#pragma unroll
            for (int rr = 0; rr < 4; ++rr) {
                int r = rg * 4 + rr, t = t0 + r;
                vb[t * HH + col] = acc[0][h][rr] + bv;
                qs[r * SP + col] = acc[1][h][rr] + bq;
                kb[t * HH + col] = acc[2][h][rr] * ks + bk;
                os[r * SP + col] = 1.f / (1.f + expf(-(acc[3][h][rr] + bo)));
            }
        }
    }
}

// ---- ff: z = lrelu([h, e] @ w_ff.T + b_ff) -> zs chunk-padded. ----
__device__ __forceinline__ void ff_block(const float* __restrict__ hsb,
        const float* __restrict__ esb, const float4* __restrict__ wff,
        const float* __restrict__ b_ff, float* __restrict__ zs) {
    int tid = threadIdx.x;
    int lane = tid & 63, wv = tid >> 6;
    int kc = lane >> 4, c = lane & 15;
    int rg = wv >> 2, cslot = (wv & 3) * 16 + c;
    float acc[2][4] = {};
    gemv128(rg, kc, cslot, hsb, wff, 0, acc);
    gemv128(rg, kc, cslot, esb, wff, 32, acc);
#pragma unroll
    for (int h = 0; h < 2; ++h)
#pragma unroll
        for (int rr = 0; rr < 4; ++rr) reduce_kc(&acc[h][rr]);
    if (kc == 0) {
#pragma unroll
        for (int h = 0; h < 2; ++h) {
            int col = cslot + 64 * h;
            float bb = b_ff[col];
#pragma unroll
            for (int rr = 0; rr < 4; ++rr) {
                int r = rg * 4 + rr;
                float a = acc[h][rr] + bb;
                a = a > 0.f ? a : 0.01f * a;
                zs[xidx(r, col)] = a;
            }
        }
    }
}

// ---- 128->128 dense: ys (LDS chunk-padded) or yg (global row-major). ----
__device__ __forceinline__ void dense128(int t0, const float* __restrict__ xls,
        const float4* __restrict__ Wp, const float* __restrict__ b,
        float* __restrict__ yg, float* __restrict__ ys) {
    int tid = threadIdx.x;
    int lane = tid & 63, wv = tid >> 6;
    int kc = lane >> 4, c = lane & 15;
    int rg = wv >> 2, cslot = (wv & 3) * 16 + c;
    float acc[2][4] = {};
    gemv128(rg, kc, cslot, xls, Wp, 0, acc);
#pragma unroll
    for (int h = 0; h < 2; ++h)
#pragma unroll
        for (int rr = 0; rr < 4; ++rr) reduce_kc(&acc[h][rr]);
    if (kc == 0) {
#pragma unroll
        for (int h = 0; h < 2; ++h) {
            int col = cslot + 64 * h;
            float bb = b[col];
#pragma unroll
            for (int rr = 0; rr < 4; ++rr) {
                int r = rg * 4 + rr;
                float a = acc[h][rr] + bb;
                if (ys) ys[xidx(r, col)] = a;
                if (yg) yg[(t0 + r) * HH + col] = a;
            }
        }
    }
}

// ---------------- fused: P0 | barrier | P1 | barrier | P2 ----------------
__global__ __launch_bounds__(512, 2) void mega_kernel(
        const float* __restrict__ emb, const int* __restrict__ start,
        const float4* __restrict__ win_p, const float* __restrict__ b_in,
        const float4* __restrict__ wcat,
        const float* __restrict__ b_v, const float* __restrict__ b_q,
        const float* __restrict__ b_k, const float* __restrict__ b_o,
        const float* __restrict__ w_f, const float* __restrict__ b_f,
        const float* __restrict__ w_i, const float* __restrict__ b_i,
        const float4* __restrict__ wff_p, const float* __restrict__ b_ff,
        const float4* __restrict__ wout_p, const float* __restrict__ b_out,
        float* __restrict__ k0b, float* __restrict__ v0b,
        float* __restrict__ k1b, float* __restrict__ v1b,
        float* __restrict__ g0, float* __restrict__ i0,
        float* __restrict__ g1, float* __restrict__ i1,
        unsigned* __restrict__ bar,
        float* __restrict__ out) {
    __shared__ float xs[ROWS * XR];
    __shared__ float es[ROWS * XR];
    __shared__ float hs[ROWS * XR];
    __shared__ float zs[ROWS * XR];
    __shared__ float qs[ROWS * SP];
    __shared__ float os[ROWS * SP];
    int tid = threadIdx.x;
    int t0 = blockIdx.x * ROWS;
    int wv = tid >> 6, lane = tid & 63;
    int d = 2 * lane;

    // ---- P0 ----
    float2 ev = *(const float2*)(emb + (t0 + wv) * HH + d);
    *(float2*)(xs + wv * XR + (d >> 5) * 36 + (d & 31)) = ev;
    __syncthreads();
    dense128(t0, xs, win_p, b_in, (float*)0, es);
    __syncthreads();
    proj_block(t0, es, wcat, b_v, b_q, b_k, b_o, k0b, v0b, qs, os);
    proj_fi(t0, es, w_f, b_f, w_i, b_i, start, g0, i0);
    grid_barrier(bar + 0);

    // ---- P1 ----
    attn_row(t0, k0b, v0b, qs, os, g0, i0, hs);
    __syncthreads();
    ff_block(hs, es, wff_p, b_ff, zs);
    __syncthreads();
    proj_block(t0, zs, wcat + 16384, b_v + HH, b_q + HH, b_k + HH, b_o + HH,
               k1b, v1b, qs, os);
    proj_fi(t0, zs, w_f + HH, b_f + 1, w_i + HH, b_i + 1, start, g1, i1);
    grid_barrier(bar + 1);

    // ---- P2 ----
    attn_row(t0, k1b, v1b, qs, os, g1, i1, hs);
    __syncthreads();
    ff_block(hs, es, wff_p + 8192, b_ff + HH, zs);
    __syncthreads();
    dense128(t0, zs, wout_p, b_out, out, (float*)0);
}

extern "C" void kernel_launch(void* const* d_in, const int* in_sizes, int n_in,
                              void* d_out, int out_size, void* d_ws, size_t ws_size,
                              hipStream_t stream) {
    const float* emb   = (const float*)d_in[0];
    const int*   start = (const int*)  d_in[1];
    const float* w_in  = (const float*)d_in[2];
    const float* b_in  = (const float*)d_in[3];
    const float* w_out = (const float*)d_in[4];
    const float* b_out = (const float*)d_in[5];
    const float* w_f   = (const float*)d_in[6];
    const float* b_f   = (const float*)d_in[7];
    const float* w_i   = (const float*)d_in[8];
    const float* b_i   = (const float*)d_in[9];
    const float* w_v   = (const float*)d_in[10];
    const float* b_v   = (const float*)d_in[11];
    const float* w_q   = (const float*)d_in[12];
    const float* b_q   = (const float*)d_in[13];
    const float* w_k   = (const float*)d_in[14];
    const float* b_k   = (const float*)d_in[15];
    const float* w_o   = (const float*)d_in[16];
    const float* b_o   = (const float*)d_in[17];
    const float* w_ff  = (const float*)d_in[18];
    const float* b_ff  = (const float*)d_in[19];
    float* out = (float*)d_out;

    unsigned* bar = (unsigned*)d_ws;            // 16 counters, zeroed by prep
    float* ws = (float*)d_ws + 64;
    float* k0b = ws; ws += TT * HH;
    float* v0b = ws; ws += TT * HH;
    float* k1b = ws; ws += TT * HH;
    float* v1b = ws; ws += TT * HH;
    float* g0  = ws; ws += TT;
    float* i0  = ws; ws += TT;
    float* g1  = ws; ws += TT;
    float* i1  = ws; ws += TT;
    float4* win_p  = (float4*)ws; ws += 16384;   // 4096 float4
    float4* wout_p = (float4*)ws; ws += 16384;   // 4096 float4
    float4* wcat   = (float4*)ws; ws += 131072;  // 32768 float4 (2 layers)
    float4* wff_p  = (float4*)ws; ws += 65536;   // 16384 float4 (2 layers)

    prep_kernel<<<dim3(224), dim3(256), 0, stream>>>(
        w_in, w_out, w_v, w_q, w_k, w_o, w_ff, win_p, wout_p, wcat, wff_p, bar);
    mega_kernel<<<dim3(NBLK), dim3(512), 0, stream>>>(
        emb, start, win_p, b_in, wcat,
        b_v, b_q, b_k, b_o, w_f, b_f, w_i, b_i,
        wff_p, b_ff, wout_p, b_out,
        k0b, v0b, k1b, v1b, g0, i0, g1, i1,
        bar, out);
}